// Round 16
// baseline (446.969 us; speedup 1.0000x reference)
//
#include <hip/hip_runtime.h>

typedef unsigned short u16;
typedef unsigned int   u32;
typedef __bf16 bf16x8 __attribute__((ext_vector_type(8)));
typedef float  f32x4  __attribute__((ext_vector_type(4)));
typedef u32    u32x4v __attribute__((ext_vector_type(4)));

#define NS 256              // samples (M)
#define KF 10000            // features (K)
#define KP 10048            // padded K
#define NO 15000            // outputs (N)
#define NP 15104            // padded N
#define BM 256
#define BN 128
#define BK 32
#define KHALF (KP/2)        // 5024
#define NSTEPS (KHALF/BK)   // 157
#define COVR 150
#define NA 100

// ---------------- prep: BatchNorm affine + fp32 -> bf16 hi/lo split ----------------
__global__ void k_prep_x(const float* __restrict__ x, const float* __restrict__ gamma,
                         const float* __restrict__ beta, const float* __restrict__ rmean,
                         const float* __restrict__ rvar,
                         u16* __restrict__ xnh, u16* __restrict__ xnl)
{
    int k = blockIdx.x * 256 + threadIdx.x;
    int s = blockIdx.y;
    if (k >= KP) return;
    float v = 0.0f;
    if (k < KF) {
        float xv = x[(size_t)s * KF + k];
        v = (xv - rmean[k]) * (gamma[k] * rsqrtf(rvar[k] + 1e-5f)) + beta[k];
    }
    u32 bits = __float_as_uint(v);
    u32 hb   = bits & 0xffff0000u;
    float lo = v - __uint_as_float(hb);
    xnh[(size_t)s * KP + k] = (u16)(hb >> 16);
    xnl[(size_t)s * KP + k] = (u16)(__float_as_uint(lo) >> 16);
}

__device__ __forceinline__ u32 pack_hi(float v0, float v1)
{
    return (__float_as_uint(v0) >> 16) | (__float_as_uint(v1) & 0xffff0000u);
}
__device__ __forceinline__ u32 pack_lo(float v0, float v1)
{
    float r0 = v0 - __uint_as_float(__float_as_uint(v0) & 0xffff0000u);
    float r1 = v1 - __uint_as_float(__float_as_uint(v1) & 0xffff0000u);
    return (__float_as_uint(r0) >> 16) | (__float_as_uint(r1) & 0xffff0000u);
}

__device__ __forceinline__ void gload16(const u16* g, u16* l)
{
    __builtin_amdgcn_global_load_lds(
        (const __attribute__((address_space(1))) void*)g,
        (__attribute__((address_space(3))) void*)l, 16, 0, 0);
}

// ---------------- GEMM: Yp[ks] = Xn * W^T (3-term bf16 split), split-K=2 --------------
// 1024 thr (16 waves, 4M x 4N, wave tile 64x32), BM=256 x BN=128, BK=32.
// B DIRECT FROM GLOBAL to registers (no LDS for B): each lane loads its MFMA
// B-fragment rows (row=l15, kchunk=lane>>4) as 2x dwordx4, splits to bf16 hi/lo
// in-register. Cuts per-step LDS traffic 240KB -> 160KB and removes the stageB
// chain. A via global_load_lds double-buffered (64KB). ONE barrier/step with
// counted vmcnt(4) (retires A(s)+B(s), keeps B(s+1) in flight).
__global__ __launch_bounds__(1024, 4) void k_gemm(
    const u16* __restrict__ xnh, const u16* __restrict__ xnl,
    const float* __restrict__ W, float* __restrict__ Yp)
{
    __shared__ u16 Ah[2][BM * BK];    // 32 KB
    __shared__ u16 Al[2][BM * BK];    // 32 KB

    const int t    = threadIdx.x;
    const int wv   = t >> 6;
    const int n0   = blockIdx.x * BN;
    const int ks   = blockIdx.y;
    const int kbeg = ks * KHALF;

    // A staging: thread t -> LDS slot t (16B), global chunk pre-swizzled
    const int rA = t >> 2;
    const int uA = t & 3;
    const int cA = uA ^ ((rA >> 1) & 3);
    const size_t eA = (size_t)rA * KP + cA * 8;

    // compute-side lane constants
    const int lane = t & 63;
    const int wm   = wv & 3;
    const int wn   = wv >> 2;
    const int l15  = lane & 15;
    const int lc   = lane >> 4;
    const int q    = (l15 >> 1) & 3;
    const int eoff = l15 * BK + ((lc ^ q) << 3);   // swizzled A elem offset

    // B direct-load constants: frag nf row = n0 + wn*32 + nf*16 + l15, k-chunk lc*8
    const int lcK = lc * 8;
    int  rowN[2];  bool rowOk[2];  size_t eB[2];
#pragma unroll
    for (int nf = 0; nf < 2; ++nf) {
        rowN[nf]  = n0 + wn * 32 + nf * 16 + l15;
        rowOk[nf] = (rowN[nf] < NO);
        eB[nf]    = (size_t)(rowOk[nf] ? rowN[nf] : 0) * KF;
    }

    f32x4 acc[4][2];
#pragma unroll
    for (int m = 0; m < 4; ++m)
#pragma unroll
        for (int n = 0; n < 2; ++n) { acc[m][n][0]=0.f; acc[m][n][1]=0.f; acc[m][n][2]=0.f; acc[m][n][3]=0.f; }

    auto issueA = [&](int nb, int kk) {
        gload16(xnh + eA + kk, Ah[nb] + (wv << 9));
        gload16(xnl + eA + kk, Al[nb] + (wv << 9));
    };
    auto loadB = [&](int kk, f32x4 (&b)[4], float (&mk)[2]) {
#pragma unroll
        for (int nf = 0; nf < 2; ++nf) {
            const bool ok = rowOk[nf] && (kk + lcK + 8 <= KF);
            const size_t a = ok ? (eB[nf] + kk + lcK) : 0;
            b[nf * 2 + 0] = *(const f32x4*)(W + a);
            b[nf * 2 + 1] = *(const f32x4*)(W + a + 4);
            mk[nf] = ok ? 1.f : 0.f;
        }
    };

    // one step; bcur = B(s) raw f32 (landed), bnext receives B(s+1)
    auto body = [&](int s, int p, bool hasNext,
                    f32x4 (&bcur)[4], float (&mkc)[2],
                    f32x4 (&bnext)[4], float (&mkn)[2])
    {
        const int nb = p ^ 1;
        const int k1 = kbeg + (s + 1) * BK;

        if (hasNext) {
            loadB(k1, bnext, mkn);   // queue: [B(s)x4, A(s)x2, B(s+1)x4]
            asm volatile("s_waitcnt vmcnt(4)" ::: "memory");   // retire A(s)+B(s)
        } else {
            asm volatile("s_waitcnt vmcnt(0)" ::: "memory");
        }
        __builtin_amdgcn_s_barrier();      // A(s) visible to all waves
        asm volatile("" ::: "memory");

        if (hasNext) { issueA(nb, k1); asm volatile("" ::: "memory"); }

        const u16* AhL = Ah[p]; const u16* AlL = Al[p];

        // ---- P1: ds_read fah; pack fbh (VALU overlaps LDS); MFMA hh ----
        bf16x8 fah[4];
#pragma unroll
        for (int m = 0; m < 4; ++m)
            fah[m] = *(const bf16x8*)(AhL + (wm * 64 + m * 16) * BK + eoff);
        bf16x8 fbh[2];
#pragma unroll
        for (int nf = 0; nf < 2; ++nf) {
            f32x4 v0 = bcur[nf * 2 + 0] * mkc[nf];
            f32x4 v1 = bcur[nf * 2 + 1] * mkc[nf];
            u32x4v h;
            h[0] = pack_hi(v0[0], v0[1]);
            h[1] = pack_hi(v0[2], v0[3]);
            h[2] = pack_hi(v1[0], v1[1]);
            h[3] = pack_hi(v1[2], v1[3]);
            fbh[nf] = *(bf16x8*)&h;
        }
        asm volatile("s_waitcnt lgkmcnt(0)" ::: "memory");
        __builtin_amdgcn_s_setprio(1);
#pragma unroll
        for (int m = 0; m < 4; ++m)
#pragma unroll
            for (int n = 0; n < 2; ++n)
                acc[m][n] = __builtin_amdgcn_mfma_f32_16x16x32_bf16(fah[m], fbh[n], acc[m][n], 0, 0, 0);
        __builtin_amdgcn_s_setprio(0);
        __builtin_amdgcn_sched_barrier(0);

        // ---- P2: pack fbl (pure VALU); MFMA hl ----
        bf16x8 fbl[2];
#pragma unroll
        for (int nf = 0; nf < 2; ++nf) {
            f32x4 v0 = bcur[nf * 2 + 0] * mkc[nf];
            f32x4 v1 = bcur[nf * 2 + 1] * mkc[nf];
            u32x4v h;
            h[0] = pack_lo(v0[0], v0[1]);
            h[1] = pack_lo(v0[2], v0[3]);
            h[2] = pack_lo(v1[0], v1[1]);
            h[3] = pack_lo(v1[2], v1[3]);
            fbl[nf] = *(bf16x8*)&h;
        }
        __builtin_amdgcn_s_setprio(1);
#pragma unroll
        for (int m = 0; m < 4; ++m)
#pragma unroll
            for (int n = 0; n < 2; ++n)
                acc[m][n] = __builtin_amdgcn_mfma_f32_16x16x32_bf16(fah[m], fbl[n], acc[m][n], 0, 0, 0);
        __builtin_amdgcn_s_setprio(0);
        __builtin_amdgcn_sched_barrier(0);

        // ---- P3: ds_read fal; MFMA lh ----
        bf16x8 fal[4];
#pragma unroll
        for (int m = 0; m < 4; ++m)
            fal[m] = *(const bf16x8*)(AlL + (wm * 64 + m * 16) * BK + eoff);
        asm volatile("s_waitcnt lgkmcnt(0)" ::: "memory");
        __builtin_amdgcn_s_setprio(1);
#pragma unroll
        for (int m = 0; m < 4; ++m)
#pragma unroll
            for (int n = 0; n < 2; ++n)
                acc[m][n] = __builtin_amdgcn_mfma_f32_16x16x32_bf16(fal[m], fbh[n], acc[m][n], 0, 0, 0);
        __builtin_amdgcn_s_setprio(0);
        __builtin_amdgcn_sched_barrier(0);
    };

    f32x4 b0[4], b1[4];
    float mk0[2], mk1[2];

    // prologue: A(0) DMA -> buf0; B(0) -> regs
    issueA(0, kbeg);
    asm volatile("" ::: "memory");
    loadB(kbeg, b0, mk0);

#pragma unroll 1
    for (int it = 0; it < (NSTEPS - 1) / 2; ++it) {   // 78 pairs: steps 0..155
        body(2 * it,     0, true, b0, mk0, b1, mk1);
        body(2 * it + 1, 1, true, b1, mk1, b0, mk0);
    }
    body(NSTEPS - 1, 0, false, b0, mk0, b1, mk1);     // step 156

    // epilogue: C/D layout col = lane&15, row = (lane>>4)*4 + reg
    const int rowb = wm * 64 + (lane >> 4) * 4;
    const int colb = n0 + wn * 32 + l15;
#pragma unroll
    for (int m = 0; m < 4; ++m)
#pragma unroll
        for (int n = 0; n < 2; ++n) {
            const size_t base = ((size_t)(ks * NS + rowb + m * 16)) * NP + colb + n * 16;
            Yp[base]          = acc[m][n][0];
            Yp[base + NP]     = acc[m][n][1];
            Yp[base + 2*NP]   = acc[m][n][2];
            Yp[base + 3*NP]   = acc[m][n][3];
        }
}

// ---------------- per-sample: fused (reduce+bias+relu) -> cov -> blocked chol -> w -----
// (unchanged from r10/r12: 39-barrier blocked Cholesky, 8x8 reg tiles, single-wave solves)
__global__ __launch_bounds__(256, 1) void k_solve(const float* __restrict__ Yp,
                                                  const float* __restrict__ bias,
                                                  float* __restrict__ out)
{
    __shared__ float Ylds[15008];
    __shared__ float Lsh[104 * 104];
    __shared__ float Lpan[104][8];
    __shared__ float panelbuf[104][8];
    __shared__ float mu[112];
    __shared__ float dgi[112];
    __shared__ float usol[112];
    __shared__ float redv[2];

    const int s = blockIdx.x;
    const int t = threadIdx.x;

    const f32x4* y04 = (const f32x4*)(Yp + (size_t)s * NP);
    const f32x4* y14 = (const f32x4*)(Yp + (size_t)(NS + s) * NP);
    const f32x4* b4  = (const f32x4*)bias;
    for (int i = t; i < 3750; i += 256) {
        f32x4 v = y04[i] + y14[i] + b4[i];
        f32x4 r;
        r[0] = fmaxf(v[0], 0.f); r[1] = fmaxf(v[1], 0.f);
        r[2] = fmaxf(v[2], 0.f); r[3] = fmaxf(v[3], 0.f);
        *(f32x4*)&Ylds[i * 4] = r;
    }
    if (t < 8) Ylds[15000 + t] = 0.f;
    if (t >= 100 && t < 112) mu[t] = 0.f;
    __syncthreads();

    if (t < NA) {
        float a = 0.f;
        for (int r = 0; r < COVR; ++r) a += Ylds[r * NA + t];
        mu[t] = a * (1.0f / COVR);
    }
    __syncthreads();

    const int ai = t >> 4;
    const int bj = t & 15;
    const int r0 = ai * 8;
    const int c0 = bj * 8;
    const bool act = (ai < 13) && (bj < 13);

    float A[8][8];
#pragma unroll
    for (int i = 0; i < 8; ++i)
#pragma unroll
        for (int j = 0; j < 8; ++j) A[i][j] = 0.f;

    if (act) {
        for (int r = 0; r < COVR; ++r) {
            const f32x4 mi0 = *(const f32x4*)&Ylds[r * NA + r0];
            const f32x4 mi1 = *(const f32x4*)&Ylds[r * NA + r0 + 4];
            const f32x4 mj0 = *(const f32x4*)&Ylds[r * NA + c0];
            const f32x4 mj1 = *(const f32x4*)&Ylds[r * NA + c0 + 4];
            float mi[8] = {mi0[0], mi0[1], mi0[2], mi0[3], mi1[0], mi1[1], mi1[2], mi1[3]};
            float mj[8] = {mj0[0], mj0[1], mj0[2], mj0[3], mj1[0], mj1[1], mj1[2], mj1[3]};
#pragma unroll
            for (int i = 0; i < 8; ++i)
#pragma unroll
                for (int j = 0; j < 8; ++j) A[i][j] += mi[i] * mj[j];
        }
        float mui[8], muj[8];
#pragma unroll
        for (int i = 0; i < 8; ++i) mui[i] = mu[r0 + i];
#pragma unroll
        for (int j = 0; j < 8; ++j) muj[j] = mu[c0 + j];
#pragma unroll
        for (int i = 0; i < 8; ++i)
#pragma unroll
            for (int j = 0; j < 8; ++j)
                A[i][j] = (A[i][j] - (float)COVR * mui[i] * muj[j]) * (1.0f / 149.0f);
#pragma unroll
        for (int i = 0; i < 8; ++i)
#pragma unroll
            for (int j = 0; j < 8; ++j)
                if (r0 + i >= NA || c0 + j >= NA)
                    A[i][j] = (r0 + i == c0 + j) ? 1.f : 0.f;
    }

    for (int p = 0; p < 13; ++p) {
        if (act && bj == p) {
#pragma unroll
            for (int i = 0; i < 8; ++i) {
                f32x4 v0, v1;
                v0[0]=A[i][0]; v0[1]=A[i][1]; v0[2]=A[i][2]; v0[3]=A[i][3];
                v1[0]=A[i][4]; v1[1]=A[i][5]; v1[2]=A[i][6]; v1[3]=A[i][7];
                *(f32x4*)&panelbuf[r0 + i][0] = v0;
                *(f32x4*)&panelbuf[r0 + i][4] = v1;
            }
        }
        __syncthreads();

        float Ld[8][8];
        float Linv[8];
#pragma unroll
        for (int k = 0; k < 8; ++k) {
            float sd = panelbuf[p * 8 + k][k];
#pragma unroll
            for (int u = 0; u < 8; ++u) if (u < k) sd -= Ld[k][u] * Ld[k][u];
            const float dk = sqrtf(sd);
            Ld[k][k] = dk;
            const float inv = 1.0f / dk;
            Linv[k] = inv;
#pragma unroll
            for (int i2 = 0; i2 < 8; ++i2) if (i2 > k) {
                float s2 = panelbuf[p * 8 + i2][k];
#pragma unroll
                for (int u = 0; u < 8; ++u) if (u < k) s2 -= Ld[i2][u] * Ld[k][u];
                Ld[i2][k] = s2 * inv;
            }
        }

        float Lr[8][8];
        if (act) {
#pragma unroll
            for (int i = 0; i < 8; ++i) {
#pragma unroll
                for (int m = 0; m < 8; ++m) {
                    float sv = panelbuf[r0 + i][m];
#pragma unroll
                    for (int u = 0; u < 8; ++u) if (u < m) sv -= Lr[i][u] * Ld[m][u];
                    Lr[i][m] = sv * Linv[m];
                }
            }
        }
        if (act && bj == 0) {
#pragma unroll
            for (int i = 0; i < 8; ++i) {
                f32x4 v0, v1;
                v0[0]=Lr[i][0]; v0[1]=Lr[i][1]; v0[2]=Lr[i][2]; v0[3]=Lr[i][3];
                v1[0]=Lr[i][4]; v1[1]=Lr[i][5]; v1[2]=Lr[i][6]; v1[3]=Lr[i][7];
                *(f32x4*)&Lpan[r0 + i][0] = v0;
                *(f32x4*)&Lpan[r0 + i][4] = v1;
            }
#pragma unroll
            for (int m = 0; m < 8; ++m)
#pragma unroll
                for (int i = 0; i < 8; ++i)
                    Lsh[(p * 8 + m) * 104 + (r0 + i)] = Lr[i][m];
        }
        if (t == 0) {
#pragma unroll
            for (int m = 0; m < 8; ++m) dgi[p * 8 + m] = Linv[m];
        }
        __syncthreads();

        if (act) {
#pragma unroll
            for (int k = 0; k < 8; ++k) {
                const f32x4 cv0 = *(const f32x4*)&Lpan[c0 + k][0];
                const f32x4 cv1 = *(const f32x4*)&Lpan[c0 + k][4];
                float Lck[8] = {cv0[0], cv0[1], cv0[2], cv0[3], cv1[0], cv1[1], cv1[2], cv1[3]};
#pragma unroll
                for (int i = 0; i < 8; ++i) {
                    float acc2 = 0.f;
#pragma unroll
                    for (int m = 0; m < 8; ++m) acc2 += Lr[i][m] * Lck[m];
                    A[i][k] -= acc2;
                }
            }
#pragma unroll
            for (int i = 0; i < 8; ++i)
#pragma unroll
                for (int j = 0; j < 8; ++j)
                    if (r0 + i >= NA || c0 + j >= NA)
                        A[i][j] = (r0 + i == c0 + j) ? 1.f : 0.f;
        }
        __syncthreads();
    }

    if (t < 64) {
        float r0c = 1.f, r1c = 1.f;
        float y0c = 0.f, y1c = 0.f;
        for (int j = 0; j < NA; ++j) {
            const float dj = dgi[j];
            float src = (j < 64) ? __shfl(r0c, j) : __shfl(r1c, j - 64);
            const float yj = src * dj;
            if (t == j) y0c = yj;
            if (t + 64 == j) y1c = yj;
            const float l0 = Lsh[j * 104 + t];
            const float l1 = Lsh[j * 104 + t + 64];
            if (t > j) r0c -= l0 * yj;
            if (t < 36 && t + 64 > j) r1c -= l1 * yj;
        }
        float u0c = 0.f, u1c = 0.f;
        for (int j = NA - 1; j >= 0; --j) {
            const float dj = dgi[j];
            float src = (j >= 64) ? __shfl(y1c, j - 64) : __shfl(y0c, j);
            const float uj = src * dj;
            if (t == j) u0c = uj;
            if (t + 64 == j) u1c = uj;
            const float l0 = Lsh[t * 104 + j];
            const float l1 = Lsh[(t + 64) * 104 + j];
            if (t < j) y0c -= l0 * uj;
            if (t < 36 && t + 64 < j) y1c -= l1 * uj;
        }
        usol[t] = u0c;
        if (t < 36) usol[t + 64] = u1c;
        float v = u0c + ((t < 36) ? u1c : 0.f);
        for (int off = 32; off > 0; off >>= 1) v += __shfl_xor(v, off);
        if (t == 0) redv[0] = 1.0f / v;
    }
    __syncthreads();
    if (t < NA) out[s * NA + t] = usol[t] * redv[0];
}

// ---------------- launcher ----------------
extern "C" void kernel_launch(void* const* d_in, const int* in_sizes, int n_in,
                              void* d_out, int out_size, void* d_ws, size_t ws_size,
                              hipStream_t stream)
{
    const float* x     = (const float*)d_in[0];
    const float* gamma = (const float*)d_in[1];
    const float* beta  = (const float*)d_in[2];
    const float* rm    = (const float*)d_in[3];
    const float* rv    = (const float*)d_in[4];
    const float* W     = (const float*)d_in[5];
    const float* b     = (const float*)d_in[6];
    float* out = (float*)d_out;

    char* ws = (char*)d_ws;
    u16*   xnh = (u16*)ws;                              // 5,144,576 B
    u16*   xnl = (u16*)(ws + 5144576);                  // 5,144,576 B
    float* Yp  = (float*)(ws + 10289152);               // 30,932,992 B
    (void)in_sizes; (void)n_in; (void)out_size; (void)ws_size;

    k_prep_x<<<dim3((KP + 255) / 256, NS), 256, 0, stream>>>(x, gamma, beta, rm, rv, xnh, xnl);
    k_gemm  <<<dim3(NP / BN, 2), 1024, 0, stream>>>(xnh, xnl, W, Yp);
    k_solve <<<dim3(NS), 256, 0, stream>>>(Yp, b, out);
}

// Round 17
// 378.654 us; speedup vs baseline: 1.1804x; 1.1804x over previous
//
#include <hip/hip_runtime.h>

typedef unsigned short u16;
typedef unsigned int   u32;
typedef _Float16 f16x8 __attribute__((ext_vector_type(8)));
typedef float  f32x4  __attribute__((ext_vector_type(4)));
typedef u32    u32x2  __attribute__((ext_vector_type(2)));

#define NS 256              // samples (M)
#define KF 10000            // features (K)
#define KP 10048            // padded K
#define NO 15000            // outputs (N)
#define NP 15104            // padded N
#define BM 256
#define BN 128
#define BK 32
#define KHALF (KP/2)        // 5024
#define NSTEPS (KHALF/BK)   // 157
#define COVR 150
#define NA 100

// ---------------- prep: BatchNorm affine -> single f16 array ----------------
__global__ void k_prep_x(const float* __restrict__ x, const float* __restrict__ gamma,
                         const float* __restrict__ beta, const float* __restrict__ rmean,
                         const float* __restrict__ rvar,
                         u16* __restrict__ xf)
{
    int k = blockIdx.x * 256 + threadIdx.x;
    int s = blockIdx.y;
    if (k >= KP) return;
    float v = 0.0f;
    if (k < KF) {
        float xv = x[(size_t)s * KF + k];
        v = (xv - rmean[k]) * (gamma[k] * rsqrtf(rvar[k] + 1e-5f)) + beta[k];
    }
    _Float16 h = (_Float16)v;
    xf[(size_t)s * KP + k] = __builtin_bit_cast(u16, h);
}

__device__ __forceinline__ void splitf16_pair(float v0, float v1, u32& hp, u32& lp)
{
    _Float16 h0 = (_Float16)v0;
    _Float16 h1 = (_Float16)v1;
    float r0 = v0 - (float)h0;
    float r1 = v1 - (float)h1;
    _Float16 l0 = (_Float16)r0;
    _Float16 l1 = (_Float16)r1;
    hp = (u32)__builtin_bit_cast(u16, h0) | ((u32)__builtin_bit_cast(u16, h1) << 16);
    lp = (u32)__builtin_bit_cast(u16, l0) | ((u32)__builtin_bit_cast(u16, l1) << 16);
}

__device__ __forceinline__ void gload16(const u16* g, u16* l)
{
    __builtin_amdgcn_global_load_lds(
        (const __attribute__((address_space(1))) void*)g,
        (__attribute__((address_space(3))) void*)l, 16, 0, 0);
}

// ---------------- GEMM: Yp[ks] = Xf16 * (64W)^T / 64, 2-term f16 split, split-K=2 -----
// 1024 thr (16 waves, 4M x 4N, wave tile 64x32), BM=256 x BN=128, BK=32, LDS 64KB.
// X single f16 (A dbuf 2x16KB via global_load_lds); W split to f16 hi/lo AT 64x SCALE
// (keeps w_lo out of subnormal flush range), staged to LDS (2x8KB each). Epilogue /64.
// r12 template minus one term: step-top {loadW; vmcnt(1); barrier}, then 2 phases
// {reads; 1 staging op; lgkm(0); barrier; setprio; 8 MFMA}.
__global__ __launch_bounds__(1024, 4) void k_gemm(
    const u16* __restrict__ xf,
    const float* __restrict__ W, float* __restrict__ Yp)
{
    __shared__ u16 Af[2][BM * BK];     // 32 KB (f16 bits)
    __shared__ u16 Bh[2][BN * BK];     // 16 KB
    __shared__ u16 Bl[2][BN * BK];     // 16 KB

    const int t    = threadIdx.x;
    const int wv   = t >> 6;
    const int n0   = blockIdx.x * BN;
    const int ks   = blockIdx.y;
    const int kbeg = ks * KHALF;

    // A staging: thread t -> LDS slot t (16B), global chunk pre-swizzled
    const int rA = t >> 2;
    const int uA = t & 3;
    const int cA = uA ^ ((rA >> 1) & 3);
    const size_t eA = (size_t)rA * KP + cA * 8;

    // W staging: thread t -> row rB, swizzled 8-elem chunk ch, half h2 (4 f32)
    const int rB  = t >> 3;
    const int ch  = (t >> 1) & 3;
    const int h2  = t & 1;
    const int gc  = ch ^ ((rB >> 1) & 3);
    const int kin = gc * 8 + h2 * 4;
    const int oW  = n0 + rB;
    const bool oOk = (oW < NO);
    const size_t eW = (size_t)(oOk ? oW : 0) * KF + kin;
    const int boff = rB * 32 + ch * 8 + h2 * 4;

    // compute-side lane constants
    const int lane = t & 63;
    const int wm   = wv & 3;
    const int wn   = wv >> 2;
    const int l15  = lane & 15;
    const int lc   = lane >> 4;
    const int q    = (l15 >> 1) & 3;
    const int eoff = l15 * BK + ((lc ^ q) << 3);

    f32x4 acc[4][2];
#pragma unroll
    for (int m = 0; m < 4; ++m)
#pragma unroll
        for (int n = 0; n < 2; ++n) { acc[m][n][0]=0.f; acc[m][n][1]=0.f; acc[m][n][2]=0.f; acc[m][n][3]=0.f; }

    auto issueA = [&](int nb, int k1) {
        gload16(xf + eA + k1, Af[nb] + (wv << 9));
    };
    auto stageB = [&](int nb, f32x4 wv4, float msk64) {
        wv4 *= msk64;                       // 64x prescale folds in here
        u32 h0, l0, h1, l1;
        splitf16_pair(wv4[0], wv4[1], h0, l0);
        splitf16_pair(wv4[2], wv4[3], h1, l1);
        u32x2 hv; hv[0] = h0; hv[1] = h1;
        u32x2 lv; lv[0] = l0; lv[1] = l1;
        *(u32x2*)(Bh[nb] + boff) = hv;
        *(u32x2*)(Bl[nb] + boff) = lv;
    };

    // prologue: A(0) DMA -> buf0; W(0) -> regs -> LDS buf0 (drains queue once)
    {
        issueA(0, kbeg);
        asm volatile("" ::: "memory");
        const bool okk = oOk && (kbeg + kin + 4 <= KF);
        const size_t wofs = okk ? (eW + kbeg) : 0;
        f32x4 w0 = *(const f32x4*)(W + wofs);
        stageB(0, w0, okk ? 64.f : 0.f);
    }

#pragma unroll 1
    for (int step = 0; step < NSTEPS; ++step) {
        const int p  = step & 1;
        const int nb = p ^ 1;
        const bool hasNext = (step + 1) < NSTEPS;
        const int k1 = kbeg + (step + 1) * BK;

        // ===== step top: load W(s+1); retire A(s); barrier =====
        f32x4 nw; float nmsk64 = 0.f;
        if (hasNext) {
            const bool okk = oOk && (k1 + kin + 4 <= KF);
            const size_t wofs = okk ? (eW + k1) : 0;
            nw = *(const f32x4*)(W + wofs);            // queue: [Af(s), nw]
            nmsk64 = okk ? 64.f : 0.f;
            asm volatile("s_waitcnt vmcnt(1)" ::: "memory");   // retire Af(s)
        } else {
            asm volatile("s_waitcnt vmcnt(0)" ::: "memory");
        }
        __builtin_amdgcn_s_barrier();
        asm volatile("" ::: "memory");

        if (hasNext) { issueA(nb, k1); asm volatile("" ::: "memory"); }

        const u16* AfL = Af[p];
        const u16* BhL = Bh[p]; const u16* BlL = Bl[p];

        // ================= Phase 1: x * Whi =================
        f16x8 fa[4], fbh[2];
#pragma unroll
        for (int m = 0; m < 4; ++m)
            fa[m] = *(const f16x8*)(AfL + (wm * 64 + m * 16) * BK + eoff);
#pragma unroll
        for (int n = 0; n < 2; ++n)
            fbh[n] = *(const f16x8*)(BhL + (wn * 32 + n * 16) * BK + eoff);
        asm volatile("s_waitcnt lgkmcnt(0)" ::: "memory");
        __builtin_amdgcn_s_barrier();
        __builtin_amdgcn_s_setprio(1);
#pragma unroll
        for (int m = 0; m < 4; ++m)
#pragma unroll
            for (int n = 0; n < 2; ++n)
                acc[m][n] = __builtin_amdgcn_mfma_f32_16x16x32_f16(fa[m], fbh[n], acc[m][n], 0, 0, 0);
        __builtin_amdgcn_s_setprio(0);
        __builtin_amdgcn_sched_barrier(0);

        // ================= Phase 2: x * Wlo =================
        f16x8 fbl[2];
#pragma unroll
        for (int n = 0; n < 2; ++n)
            fbl[n] = *(const f16x8*)(BlL + (wn * 32 + n * 16) * BK + eoff);
        if (hasNext) stageB(nb, nw, nmsk64);   // compiler vmcnt(1) waits nw; Af(s+1) rides
        asm volatile("s_waitcnt lgkmcnt(0)" ::: "memory");
        __builtin_amdgcn_s_barrier();
        __builtin_amdgcn_s_setprio(1);
#pragma unroll
        for (int m = 0; m < 4; ++m)
#pragma unroll
            for (int n = 0; n < 2; ++n)
                acc[m][n] = __builtin_amdgcn_mfma_f32_16x16x32_f16(fa[m], fbl[n], acc[m][n], 0, 0, 0);
        __builtin_amdgcn_s_setprio(0);
        __builtin_amdgcn_sched_barrier(0);
    }

    // epilogue: undo 64x W prescale; C/D layout col = lane&15, row = (lane>>4)*4 + reg
    const int rowb = wm * 64 + lc * 4;
    const int colb = n0 + wn * 32 + l15;
#pragma unroll
    for (int m = 0; m < 4; ++m)
#pragma unroll
        for (int n = 0; n < 2; ++n) {
            const size_t base = ((size_t)(ks * NS + rowb + m * 16)) * NP + colb + n * 16;
            Yp[base]          = acc[m][n][0] * 0.015625f;
            Yp[base + NP]     = acc[m][n][1] * 0.015625f;
            Yp[base + 2*NP]   = acc[m][n][2] * 0.015625f;
            Yp[base + 3*NP]   = acc[m][n][3] * 0.015625f;
        }
}

// ---------------- per-sample: fused (reduce+bias+relu) -> cov -> blocked chol -> w -----
// (unchanged from r10/r12: 39-barrier blocked Cholesky, 8x8 reg tiles, single-wave solves)
__global__ __launch_bounds__(256, 1) void k_solve(const float* __restrict__ Yp,
                                                  const float* __restrict__ bias,
                                                  float* __restrict__ out)
{
    __shared__ float Ylds[15008];
    __shared__ float Lsh[104 * 104];
    __shared__ float Lpan[104][8];
    __shared__ float panelbuf[104][8];
    __shared__ float mu[112];
    __shared__ float dgi[112];
    __shared__ float usol[112];
    __shared__ float redv[2];

    const int s = blockIdx.x;
    const int t = threadIdx.x;

    const f32x4* y04 = (const f32x4*)(Yp + (size_t)s * NP);
    const f32x4* y14 = (const f32x4*)(Yp + (size_t)(NS + s) * NP);
    const f32x4* b4  = (const f32x4*)bias;
    for (int i = t; i < 3750; i += 256) {
        f32x4 v = y04[i] + y14[i] + b4[i];
        f32x4 r;
        r[0] = fmaxf(v[0], 0.f); r[1] = fmaxf(v[1], 0.f);
        r[2] = fmaxf(v[2], 0.f); r[3] = fmaxf(v[3], 0.f);
        *(f32x4*)&Ylds[i * 4] = r;
    }
    if (t < 8) Ylds[15000 + t] = 0.f;
    if (t >= 100 && t < 112) mu[t] = 0.f;
    __syncthreads();

    if (t < NA) {
        float a = 0.f;
        for (int r = 0; r < COVR; ++r) a += Ylds[r * NA + t];
        mu[t] = a * (1.0f / COVR);
    }
    __syncthreads();

    const int ai = t >> 4;
    const int bj = t & 15;
    const int r0 = ai * 8;
    const int c0 = bj * 8;
    const bool act = (ai < 13) && (bj < 13);

    float A[8][8];
#pragma unroll
    for (int i = 0; i < 8; ++i)
#pragma unroll
        for (int j = 0; j < 8; ++j) A[i][j] = 0.f;

    if (act) {
        for (int r = 0; r < COVR; ++r) {
            const f32x4 mi0 = *(const f32x4*)&Ylds[r * NA + r0];
            const f32x4 mi1 = *(const f32x4*)&Ylds[r * NA + r0 + 4];
            const f32x4 mj0 = *(const f32x4*)&Ylds[r * NA + c0];
            const f32x4 mj1 = *(const f32x4*)&Ylds[r * NA + c0 + 4];
            float mi[8] = {mi0[0], mi0[1], mi0[2], mi0[3], mi1[0], mi1[1], mi1[2], mi1[3]};
            float mj[8] = {mj0[0], mj0[1], mj0[2], mj0[3], mj1[0], mj1[1], mj1[2], mj1[3]};
#pragma unroll
            for (int i = 0; i < 8; ++i)
#pragma unroll
                for (int j = 0; j < 8; ++j) A[i][j] += mi[i] * mj[j];
        }
        float mui[8], muj[8];
#pragma unroll
        for (int i = 0; i < 8; ++i) mui[i] = mu[r0 + i];
#pragma unroll
        for (int j = 0; j < 8; ++j) muj[j] = mu[c0 + j];
#pragma unroll
        for (int i = 0; i < 8; ++i)
#pragma unroll
            for (int j = 0; j < 8; ++j)
                A[i][j] = (A[i][j] - (float)COVR * mui[i] * muj[j]) * (1.0f / 149.0f);
#pragma unroll
        for (int i = 0; i < 8; ++i)
#pragma unroll
            for (int j = 0; j < 8; ++j)
                if (r0 + i >= NA || c0 + j >= NA)
                    A[i][j] = (r0 + i == c0 + j) ? 1.f : 0.f;
    }

    for (int p = 0; p < 13; ++p) {
        if (act && bj == p) {
#pragma unroll
            for (int i = 0; i < 8; ++i) {
                f32x4 v0, v1;
                v0[0]=A[i][0]; v0[1]=A[i][1]; v0[2]=A[i][2]; v0[3]=A[i][3];
                v1[0]=A[i][4]; v1[1]=A[i][5]; v1[2]=A[i][6]; v1[3]=A[i][7];
                *(f32x4*)&panelbuf[r0 + i][0] = v0;
                *(f32x4*)&panelbuf[r0 + i][4] = v1;
            }
        }
        __syncthreads();

        float Ld[8][8];
        float Linv[8];
#pragma unroll
        for (int k = 0; k < 8; ++k) {
            float sd = panelbuf[p * 8 + k][k];
#pragma unroll
            for (int u = 0; u < 8; ++u) if (u < k) sd -= Ld[k][u] * Ld[k][u];
            const float dk = sqrtf(sd);
            Ld[k][k] = dk;
            const float inv = 1.0f / dk;
            Linv[k] = inv;
#pragma unroll
            for (int i2 = 0; i2 < 8; ++i2) if (i2 > k) {
                float s2 = panelbuf[p * 8 + i2][k];
#pragma unroll
                for (int u = 0; u < 8; ++u) if (u < k) s2 -= Ld[i2][u] * Ld[k][u];
                Ld[i2][k] = s2 * inv;
            }
        }

        float Lr[8][8];
        if (act) {
#pragma unroll
            for (int i = 0; i < 8; ++i) {
#pragma unroll
                for (int m = 0; m < 8; ++m) {
                    float sv = panelbuf[r0 + i][m];
#pragma unroll
                    for (int u = 0; u < 8; ++u) if (u < m) sv -= Lr[i][u] * Ld[m][u];
                    Lr[i][m] = sv * Linv[m];
                }
            }
        }
        if (act && bj == 0) {
#pragma unroll
            for (int i = 0; i < 8; ++i) {
                f32x4 v0, v1;
                v0[0]=Lr[i][0]; v0[1]=Lr[i][1]; v0[2]=Lr[i][2]; v0[3]=Lr[i][3];
                v1[0]=Lr[i][4]; v1[1]=Lr[i][5]; v1[2]=Lr[i][6]; v1[3]=Lr[i][7];
                *(f32x4*)&Lpan[r0 + i][0] = v0;
                *(f32x4*)&Lpan[r0 + i][4] = v1;
            }
#pragma unroll
            for (int m = 0; m < 8; ++m)
#pragma unroll
                for (int i = 0; i < 8; ++i)
                    Lsh[(p * 8 + m) * 104 + (r0 + i)] = Lr[i][m];
        }
        if (t == 0) {
#pragma unroll
            for (int m = 0; m < 8; ++m) dgi[p * 8 + m] = Linv[m];
        }
        __syncthreads();

        if (act) {
#pragma unroll
            for (int k = 0; k < 8; ++k) {
                const f32x4 cv0 = *(const f32x4*)&Lpan[c0 + k][0];
                const f32x4 cv1 = *(const f32x4*)&Lpan[c0 + k][4];
                float Lck[8] = {cv0[0], cv0[1], cv0[2], cv0[3], cv1[0], cv1[1], cv1[2], cv1[3]};
#pragma unroll
                for (int i = 0; i < 8; ++i) {
                    float acc2 = 0.f;
#pragma unroll
                    for (int m = 0; m < 8; ++m) acc2 += Lr[i][m] * Lck[m];
                    A[i][k] -= acc2;
                }
            }
#pragma unroll
            for (int i = 0; i < 8; ++i)
#pragma unroll
                for (int j = 0; j < 8; ++j)
                    if (r0 + i >= NA || c0 + j >= NA)
                        A[i][j] = (r0 + i == c0 + j) ? 1.f : 0.f;
        }
        __syncthreads();
    }

    if (t < 64) {
        float r0c = 1.f, r1c = 1.f;
        float y0c = 0.f, y1c = 0.f;
        for (int j = 0; j < NA; ++j) {
            const float dj = dgi[j];
            float src = (j < 64) ? __shfl(r0c, j) : __shfl(r1c, j - 64);
            const float yj = src * dj;
            if (t == j) y0c = yj;
            if (t + 64 == j) y1c = yj;
            const float l0 = Lsh[j * 104 + t];
            const float l1 = Lsh[j * 104 + t + 64];
            if (t > j) r0c -= l0 * yj;
            if (t < 36 && t + 64 > j) r1c -= l1 * yj;
        }
        float u0c = 0.f, u1c = 0.f;
        for (int j = NA - 1; j >= 0; --j) {
            const float dj = dgi[j];
            float src = (j >= 64) ? __shfl(y1c, j - 64) : __shfl(y0c, j);
            const float uj = src * dj;
            if (t == j) u0c = uj;
            if (t + 64 == j) u1c = uj;
            const float l0 = Lsh[t * 104 + j];
            const float l1 = Lsh[(t + 64) * 104 + j];
            if (t < j) y0c -= l0 * uj;
            if (t < 36 && t + 64 < j) y1c -= l1 * uj;
        }
        usol[t] = u0c;
        if (t < 36) usol[t + 64] = u1c;
        float v = u0c + ((t < 36) ? u1c : 0.f);
        for (int off = 32; off > 0; off >>= 1) v += __shfl_xor(v, off);
        if (t == 0) redv[0] = 1.0f / v;
    }
    __syncthreads();
    if (t < NA) out[s * NA + t] = usol[t] * redv[0];
}

// ---------------- launcher ----------------
extern "C" void kernel_launch(void* const* d_in, const int* in_sizes, int n_in,
                              void* d_out, int out_size, void* d_ws, size_t ws_size,
                              hipStream_t stream)
{
    const float* x     = (const float*)d_in[0];
    const float* gamma = (const float*)d_in[1];
    const float* beta  = (const float*)d_in[2];
    const float* rm    = (const float*)d_in[3];
    const float* rv    = (const float*)d_in[4];
    const float* W     = (const float*)d_in[5];
    const float* b     = (const float*)d_in[6];
    float* out = (float*)d_out;

    char* ws = (char*)d_ws;
    u16*   xf = (u16*)ws;                               // 256*10048*2 = 5,144,576 B
    float* Yp = (float*)(ws + 5144576);                 // 30,932,992 B
    (void)in_sizes; (void)n_in; (void)out_size; (void)ws_size;

    k_prep_x<<<dim3((KP + 255) / 256, NS), 256, 0, stream>>>(x, gamma, beta, rm, rv, xf);
    k_gemm  <<<dim3(NP / BN, 2), 1024, 0, stream>>>(xf, W, Yp);
    k_solve <<<dim3(NS), 256, 0, stream>>>(Yp, b, out);
}